// Round 4
// baseline (106.576 us; speedup 1.0000x reference)
//
#include <hip/hip_runtime.h>
#include <math.h>

#define ROWS_TOTAL 8192
#define KDIM 4096
#define NJ 25          // 4 pre + 4 post + 16 res + 1 ssq
#define BM 128         // rows per block (8 waves x 16 rows)
#define NTHREADS 512

typedef __attribute__((ext_vector_type(8))) short bf16x8;
typedef __attribute__((ext_vector_type(4))) float f32x4;

__device__ __forceinline__ unsigned short f2bf(float f) {
    union { float f; unsigned u; } v; v.f = f;
    unsigned r = (v.u + 0x7FFFu + ((v.u >> 16) & 1u)) >> 16;
    return (unsigned short)r;
}

union BF {
    uint4 u4;
    bf16x8 h;
};

// ------------------------------------------------------------------
// Kernel 1: bf16 MFMA projection + fp32 ssq.
// grid = 64 row-groups x KSPLIT k-slices. 512 threads (8 waves).
// KSPLIT=16: KQ=256, staged-B LDS = 16KB -> 4 blocks/CU -> 32 waves/CU.
// B (phi*w, KQ k x 32 cols; cols: 0-3 pre, 4-7 post, 8-23 res, 24-31 pad)
// staged once per block in MFMA-fragment order.
// A (x) loaded global->reg per K-step, coalesced dwordx4, no main-loop
// barriers; ssq kept exact fp32 + shfl_xor reduce.
// ws layout: ws[slice][j(25)][row(8192)]
// ------------------------------------------------------------------
template<int KSPLIT>
__global__ __launch_bounds__(NTHREADS) void mhc_main(
    const float* __restrict__ x,
    const float* __restrict__ rmsw,
    const float* __restrict__ phi_pre,
    const float* __restrict__ phi_post,
    const float* __restrict__ phi_res,
    float* __restrict__ ws)
{
    constexpr int KQ  = KDIM / KSPLIT;   // k per block
    constexpr int NS  = KQ / 32;         // K-steps
    constexpr int FPT = NS * 2 * 64 / NTHREADS;  // frags per thread

    __shared__ uint4 bfrag[NS * 2 * 64];

    const int t    = threadIdx.x;
    const int wave = t >> 6;
    const int lane = t & 63;
    const int bid  = blockIdx.x;
    const int g    = bid / KSPLIT;       // row group 0..63
    const int q    = bid % KSPLIT;       // k slice
    const int kq0  = q * KQ;

    // ---- stage B fragments (one-time) ----
    #pragma unroll
    for (int f = 0; f < FPT; ++f) {
        const int fid = f * NTHREADS + t;
        const int s   = fid >> 7;               // K-step
        const int n   = (fid >> 6) & 1;         // col tile
        const int ln  = fid & 63;               // frag lane
        const int col = n * 16 + (ln & 15);
        const int kl  = s * 32 + 8 * (ln >> 4);
        unsigned short e[8];
        #pragma unroll
        for (int j = 0; j < 8; ++j) {
            const int k = kq0 + kl + j;
            float v = 0.f;
            if (col < 4)       v = rmsw[k] * phi_pre[k * 4 + col];
            else if (col < 8)  v = rmsw[k] * phi_post[k * 4 + (col - 4)];
            else if (col < 24) v = rmsw[k] * phi_res[k * 16 + (col - 8)];
            e[j] = f2bf(v);
        }
        uint4 pk;
        pk.x = (unsigned)e[0] | ((unsigned)e[1] << 16);
        pk.y = (unsigned)e[2] | ((unsigned)e[3] << 16);
        pk.z = (unsigned)e[4] | ((unsigned)e[5] << 16);
        pk.w = (unsigned)e[6] | ((unsigned)e[7] << 16);
        bfrag[(s * 2 + n) * 64 + ln] = pk;
    }
    __syncthreads();

    // ---- main loop ----
    const int row = g * BM + wave * 16 + (lane & 15);
    const float* xr = x + (size_t)row * KDIM + kq0 + 8 * (lane >> 4);

    f32x4 acc0 = {0.f, 0.f, 0.f, 0.f};
    f32x4 acc1 = {0.f, 0.f, 0.f, 0.f};
    float ssq = 0.f;

    #pragma unroll 4
    for (int s = 0; s < NS; ++s) {
        const float4 a0 = *(const float4*)(xr + 32 * s);
        const float4 a1 = *(const float4*)(xr + 32 * s + 4);
        ssq = fmaf(a0.x, a0.x, ssq);
        ssq = fmaf(a0.y, a0.y, ssq);
        ssq = fmaf(a0.z, a0.z, ssq);
        ssq = fmaf(a0.w, a0.w, ssq);
        ssq = fmaf(a1.x, a1.x, ssq);
        ssq = fmaf(a1.y, a1.y, ssq);
        ssq = fmaf(a1.z, a1.z, ssq);
        ssq = fmaf(a1.w, a1.w, ssq);
        BF af;
        af.u4.x = (unsigned)f2bf(a0.x) | ((unsigned)f2bf(a0.y) << 16);
        af.u4.y = (unsigned)f2bf(a0.z) | ((unsigned)f2bf(a0.w) << 16);
        af.u4.z = (unsigned)f2bf(a1.x) | ((unsigned)f2bf(a1.y) << 16);
        af.u4.w = (unsigned)f2bf(a1.z) | ((unsigned)f2bf(a1.w) << 16);
        BF b0, b1;
        b0.u4 = bfrag[(s * 2 + 0) * 64 + lane];
        b1.u4 = bfrag[(s * 2 + 1) * 64 + lane];
        acc0 = __builtin_amdgcn_mfma_f32_16x16x32_bf16(af.h, b0.h, acc0, 0, 0, 0);
        acc1 = __builtin_amdgcn_mfma_f32_16x16x32_bf16(af.h, b1.h, acc1, 0, 0, 0);
    }

    // ssq: combine the 4 k-offset groups (rows identical across l>>4)
    ssq += __shfl_xor(ssq, 16);
    ssq += __shfl_xor(ssq, 32);

    // ---- write partials: C/D layout col=lane&15, row=4*(lane>>4)+reg ----
    float* wsq = ws + (size_t)q * (NJ * ROWS_TOTAL);
    const int rbase = g * BM + wave * 16 + 4 * (lane >> 4);
    const int c0 = lane & 15;
    #pragma unroll
    for (int r = 0; r < 4; ++r)
        wsq[c0 * ROWS_TOTAL + rbase + r] = acc0[r];
    if (c0 < 8) {
        #pragma unroll
        for (int r = 0; r < 4; ++r)
            wsq[(16 + c0) * ROWS_TOTAL + rbase + r] = acc1[r];
    }
    if (lane < 16)
        wsq[24 * ROWS_TOTAL + g * BM + wave * 16 + lane] = ssq;
}

// ------------------------------------------------------------------
// Kernel 2: combine KSPLIT partials, RMS scale, sigmoids, Sinkhorn.
// One thread per row; 128 blocks x 64 threads.
// ------------------------------------------------------------------
__device__ __forceinline__ float sigmoidf_(float z) {
    return 1.f / (1.f + __expf(-z));
}

template<int KSPLIT>
__global__ __launch_bounds__(64) void mhc_epi(
    const float* __restrict__ ws,
    const float* __restrict__ b_pre,
    const float* __restrict__ b_post,
    const float* __restrict__ b_res,
    const float* __restrict__ a_pre,
    const float* __restrict__ a_post,
    const float* __restrict__ a_res,
    float* __restrict__ out)
{
    const int r = blockIdx.x * 64 + threadIdx.x;   // 0..8191
    float d[NJ];
    #pragma unroll
    for (int j = 0; j < NJ; ++j) {
        float s = 0.f;
        #pragma unroll
        for (int qq = 0; qq < KSPLIT; ++qq)
            s += ws[(size_t)qq * (NJ * ROWS_TOTAL) + (size_t)j * ROWS_TOTAL + r];
        d[j] = s;
    }
    const float scale = rsqrtf(d[24] * (1.0f / KDIM) + 1e-6f);
    const float ap  = a_pre[0] * scale;
    const float apo = a_post[0] * scale;
    const float ar  = a_res[0] * scale;

    float4 o0, o1;
    o0.x = sigmoidf_(fmaf(ap, d[0], b_pre[0]));
    o0.y = sigmoidf_(fmaf(ap, d[1], b_pre[1]));
    o0.z = sigmoidf_(fmaf(ap, d[2], b_pre[2]));
    o0.w = sigmoidf_(fmaf(ap, d[3], b_pre[3]));
    o1.x = 2.f * sigmoidf_(fmaf(apo, d[4], b_post[0]));
    o1.y = 2.f * sigmoidf_(fmaf(apo, d[5], b_post[1]));
    o1.z = 2.f * sigmoidf_(fmaf(apo, d[6], b_post[2]));
    o1.w = 2.f * sigmoidf_(fmaf(apo, d[7], b_post[3]));

    float m[16];
    #pragma unroll
    for (int i = 0; i < 16; ++i)
        m[i] = __expf(fmaf(ar, d[8 + i], b_res[i]));

    for (int it = 0; it < 20; ++it) {
        #pragma unroll
        for (int i = 0; i < 4; ++i) {           // row normalize
            const float s = m[4*i] + m[4*i+1] + m[4*i+2] + m[4*i+3];
            const float inv = 1.f / s;
            m[4*i] *= inv; m[4*i+1] *= inv; m[4*i+2] *= inv; m[4*i+3] *= inv;
        }
        #pragma unroll
        for (int i = 0; i < 4; ++i) {           // col normalize
            const float s = m[i] + m[4+i] + m[8+i] + m[12+i];
            const float inv = 1.f / s;
            m[i] *= inv; m[4+i] *= inv; m[8+i] *= inv; m[12+i] *= inv;
        }
    }

    float* o_pre  = out;
    float* o_post = out + 32768;
    float* o_res  = out + 65536;
    ((float4*)o_pre)[r]  = o0;
    ((float4*)o_post)[r] = o1;
    #pragma unroll
    for (int i = 0; i < 4; ++i)
        ((float4*)o_res)[r * 4 + i] = make_float4(m[4*i], m[4*i+1], m[4*i+2], m[4*i+3]);
}

extern "C" void kernel_launch(void* const* d_in, const int* in_sizes, int n_in,
                              void* d_out, int out_size, void* d_ws, size_t ws_size,
                              hipStream_t stream) {
    const float* x      = (const float*)d_in[0];
    const float* rmsw   = (const float*)d_in[1];
    const float* ppre   = (const float*)d_in[2];
    const float* ppost  = (const float*)d_in[3];
    const float* pres   = (const float*)d_in[4];
    const float* b_pre  = (const float*)d_in[5];
    const float* b_post = (const float*)d_in[6];
    const float* b_res  = (const float*)d_in[7];
    const float* a_pre  = (const float*)d_in[8];
    const float* a_post = (const float*)d_in[9];
    const float* a_res  = (const float*)d_in[10];
    float* ws  = (float*)d_ws;
    float* out = (float*)d_out;

    const size_t need16 = (size_t)16 * NJ * ROWS_TOTAL * 4;   // 13.1 MB
    if (ws_size >= need16) {
        hipLaunchKernelGGL((mhc_main<16>), dim3(64 * 16), dim3(NTHREADS), 0, stream,
                           x, rmsw, ppre, ppost, pres, ws);
        hipLaunchKernelGGL((mhc_epi<16>), dim3(128), dim3(64), 0, stream,
                           ws, b_pre, b_post, b_res, a_pre, a_post, a_res, out);
    } else {
        hipLaunchKernelGGL((mhc_main<4>), dim3(64 * 4), dim3(NTHREADS), 0, stream,
                           x, rmsw, ppre, ppost, pres, ws);
        hipLaunchKernelGGL((mhc_epi<4>), dim3(128), dim3(64), 0, stream,
                           ws, b_pre, b_post, b_res, a_pre, a_post, a_res, out);
    }
}

// Round 5
// 43.450 us; speedup vs baseline: 2.4528x; 2.4528x over previous
//
#include <hip/hip_runtime.h>
#include <math.h>

#define ROWS_TOTAL 8192
#define KDIM 4096
#define NJ 25          // 4 pre + 4 post + 16 res + 1 ssq
#define BM 128         // rows per block (8 waves x 16 rows)
#define NTHREADS 512

typedef __attribute__((ext_vector_type(8))) short bf16x8;
typedef __attribute__((ext_vector_type(4))) float f32x4;

__device__ __forceinline__ unsigned short f2bf(float f) {
    union { float f; unsigned u; } v; v.f = f;
    unsigned r = (v.u + 0x7FFFu + ((v.u >> 16) & 1u)) >> 16;
    return (unsigned short)r;
}

union BF {
    uint4 u4;
    bf16x8 h;
};

// ------------------------------------------------------------------
// Kernel 1: bf16 MFMA projection + fp32 ssq.
// grid = 64 row-groups x KSPLIT k-slices. 512 threads (8 waves).
// KSPLIT=16: KQ=256, staged-B LDS = 16KB -> 4 blocks/CU -> 32 waves/CU.
// B (phi*w, KQ k x 32 cols; cols: 0-3 pre, 4-7 post, 8-23 res, 24-31 pad)
// staged once per block in MFMA-fragment order.
// A (x) loaded global->reg per K-step, coalesced dwordx4, no main-loop
// barriers; ssq kept exact fp32 + shfl_xor reduce.
// ws layout: ws[slice][j(25)][row(8192)]
// ------------------------------------------------------------------
template<int KSPLIT>
__global__ __launch_bounds__(NTHREADS) void mhc_main(
    const float* __restrict__ x,
    const float* __restrict__ rmsw,
    const float* __restrict__ phi_pre,
    const float* __restrict__ phi_post,
    const float* __restrict__ phi_res,
    float* __restrict__ ws)
{
    constexpr int KQ  = KDIM / KSPLIT;   // k per block
    constexpr int NS  = KQ / 32;         // K-steps
    constexpr int FPT = NS * 2 * 64 / NTHREADS;  // frags per thread

    __shared__ uint4 bfrag[NS * 2 * 64];

    const int t    = threadIdx.x;
    const int wave = t >> 6;
    const int lane = t & 63;
    const int bid  = blockIdx.x;
    const int g    = bid / KSPLIT;       // row group 0..63
    const int q    = bid % KSPLIT;       // k slice
    const int kq0  = q * KQ;

    // ---- stage B fragments (one-time) ----
    #pragma unroll
    for (int f = 0; f < FPT; ++f) {
        const int fid = f * NTHREADS + t;
        const int s   = fid >> 7;               // K-step
        const int n   = (fid >> 6) & 1;         // col tile
        const int ln  = fid & 63;               // frag lane
        const int col = n * 16 + (ln & 15);
        const int kl  = s * 32 + 8 * (ln >> 4);
        unsigned short e[8];
        #pragma unroll
        for (int j = 0; j < 8; ++j) {
            const int k = kq0 + kl + j;
            float v = 0.f;
            if (col < 4)       v = rmsw[k] * phi_pre[k * 4 + col];
            else if (col < 8)  v = rmsw[k] * phi_post[k * 4 + (col - 4)];
            else if (col < 24) v = rmsw[k] * phi_res[k * 16 + (col - 8)];
            e[j] = f2bf(v);
        }
        uint4 pk;
        pk.x = (unsigned)e[0] | ((unsigned)e[1] << 16);
        pk.y = (unsigned)e[2] | ((unsigned)e[3] << 16);
        pk.z = (unsigned)e[4] | ((unsigned)e[5] << 16);
        pk.w = (unsigned)e[6] | ((unsigned)e[7] << 16);
        bfrag[(s * 2 + n) * 64 + ln] = pk;
    }
    __syncthreads();

    // ---- main loop ----
    const int row = g * BM + wave * 16 + (lane & 15);
    const float* xr = x + (size_t)row * KDIM + kq0 + 8 * (lane >> 4);

    f32x4 acc0 = {0.f, 0.f, 0.f, 0.f};
    f32x4 acc1 = {0.f, 0.f, 0.f, 0.f};
    float ssq = 0.f;

    #pragma unroll 4
    for (int s = 0; s < NS; ++s) {
        const float4 a0 = *(const float4*)(xr + 32 * s);
        const float4 a1 = *(const float4*)(xr + 32 * s + 4);
        ssq = fmaf(a0.x, a0.x, ssq);
        ssq = fmaf(a0.y, a0.y, ssq);
        ssq = fmaf(a0.z, a0.z, ssq);
        ssq = fmaf(a0.w, a0.w, ssq);
        ssq = fmaf(a1.x, a1.x, ssq);
        ssq = fmaf(a1.y, a1.y, ssq);
        ssq = fmaf(a1.z, a1.z, ssq);
        ssq = fmaf(a1.w, a1.w, ssq);
        BF af;
        af.u4.x = (unsigned)f2bf(a0.x) | ((unsigned)f2bf(a0.y) << 16);
        af.u4.y = (unsigned)f2bf(a0.z) | ((unsigned)f2bf(a0.w) << 16);
        af.u4.z = (unsigned)f2bf(a1.x) | ((unsigned)f2bf(a1.y) << 16);
        af.u4.w = (unsigned)f2bf(a1.z) | ((unsigned)f2bf(a1.w) << 16);
        BF b0, b1;
        b0.u4 = bfrag[(s * 2 + 0) * 64 + lane];
        b1.u4 = bfrag[(s * 2 + 1) * 64 + lane];
        acc0 = __builtin_amdgcn_mfma_f32_16x16x32_bf16(af.h, b0.h, acc0, 0, 0, 0);
        acc1 = __builtin_amdgcn_mfma_f32_16x16x32_bf16(af.h, b1.h, acc1, 0, 0, 0);
    }

    // ssq: combine the 4 k-offset groups (rows identical across l>>4)
    ssq += __shfl_xor(ssq, 16);
    ssq += __shfl_xor(ssq, 32);

    // ---- write partials: C/D layout col=lane&15, row=4*(lane>>4)+reg ----
    float* wsq = ws + (size_t)q * (NJ * ROWS_TOTAL);
    const int rbase = g * BM + wave * 16 + 4 * (lane >> 4);
    const int c0 = lane & 15;
    #pragma unroll
    for (int r = 0; r < 4; ++r)
        wsq[c0 * ROWS_TOTAL + rbase + r] = acc0[r];
    if (c0 < 8) {
        #pragma unroll
        for (int r = 0; r < 4; ++r)
            wsq[(16 + c0) * ROWS_TOTAL + rbase + r] = acc1[r];
    }
    if (lane < 16)
        wsq[24 * ROWS_TOTAL + g * BM + wave * 16 + lane] = ssq;
}

// ------------------------------------------------------------------
// Kernel 1.5: reduce KSPLIT partial slices -> dsum[j][row].
// One thread per (j,row): 25*8192 = 204800 threads (400 blocks x 512).
// All loads/stores coalesced; 3200 waves hide latency.
// ------------------------------------------------------------------
template<int KSPLIT>
__global__ __launch_bounds__(NTHREADS) void mhc_reduce(
    const float* __restrict__ ws,
    float* __restrict__ dsum)
{
    const int tg = blockIdx.x * NTHREADS + threadIdx.x;   // 0..204799
    if (tg >= NJ * ROWS_TOTAL) return;
    float s = 0.f;
    #pragma unroll
    for (int qq = 0; qq < KSPLIT; ++qq)
        s += ws[(size_t)qq * (NJ * ROWS_TOTAL) + tg];
    dsum[tg] = s;
}

// ------------------------------------------------------------------
// Kernel 2: RMS scale, sigmoids, Sinkhorn. One thread per row.
// 128 blocks x 64 threads; dsum staged through LDS with coalesced loads.
// ------------------------------------------------------------------
__device__ __forceinline__ float sigmoidf_(float z) {
    return 1.f / (1.f + __expf(-z));
}

__global__ __launch_bounds__(64) void mhc_epi(
    const float* __restrict__ dsum,
    const float* __restrict__ b_pre,
    const float* __restrict__ b_post,
    const float* __restrict__ b_res,
    const float* __restrict__ a_pre,
    const float* __restrict__ a_post,
    const float* __restrict__ a_res,
    float* __restrict__ out)
{
    __shared__ float sm[NJ * 64];
    const int lane = threadIdx.x;
    const int r0   = blockIdx.x * 64;
    const int r    = r0 + lane;           // 0..8191

    #pragma unroll
    for (int j = 0; j < NJ; ++j)
        sm[j * 64 + lane] = dsum[j * ROWS_TOTAL + r0 + lane];
    __syncthreads();

    float d[NJ];
    #pragma unroll
    for (int j = 0; j < NJ; ++j)
        d[j] = sm[j * 64 + lane];

    const float scale = rsqrtf(d[24] * (1.0f / KDIM) + 1e-6f);
    const float ap  = a_pre[0] * scale;
    const float apo = a_post[0] * scale;
    const float ar  = a_res[0] * scale;

    float4 o0, o1;
    o0.x = sigmoidf_(fmaf(ap, d[0], b_pre[0]));
    o0.y = sigmoidf_(fmaf(ap, d[1], b_pre[1]));
    o0.z = sigmoidf_(fmaf(ap, d[2], b_pre[2]));
    o0.w = sigmoidf_(fmaf(ap, d[3], b_pre[3]));
    o1.x = 2.f * sigmoidf_(fmaf(apo, d[4], b_post[0]));
    o1.y = 2.f * sigmoidf_(fmaf(apo, d[5], b_post[1]));
    o1.z = 2.f * sigmoidf_(fmaf(apo, d[6], b_post[2]));
    o1.w = 2.f * sigmoidf_(fmaf(apo, d[7], b_post[3]));

    float m[16];
    #pragma unroll
    for (int i = 0; i < 16; ++i)
        m[i] = __expf(fmaf(ar, d[8 + i], b_res[i]));

    for (int it = 0; it < 20; ++it) {
        #pragma unroll
        for (int i = 0; i < 4; ++i) {           // row normalize
            const float s = m[4*i] + m[4*i+1] + m[4*i+2] + m[4*i+3];
            const float inv = 1.f / s;
            m[4*i] *= inv; m[4*i+1] *= inv; m[4*i+2] *= inv; m[4*i+3] *= inv;
        }
        #pragma unroll
        for (int i = 0; i < 4; ++i) {           // col normalize
            const float s = m[i] + m[4+i] + m[8+i] + m[12+i];
            const float inv = 1.f / s;
            m[i] *= inv; m[4+i] *= inv; m[8+i] *= inv; m[12+i] *= inv;
        }
    }

    float* o_pre  = out;
    float* o_post = out + 32768;
    float* o_res  = out + 65536;
    ((float4*)o_pre)[r]  = o0;
    ((float4*)o_post)[r] = o1;
    #pragma unroll
    for (int i = 0; i < 4; ++i)
        ((float4*)o_res)[r * 4 + i] = make_float4(m[4*i], m[4*i+1], m[4*i+2], m[4*i+3]);
}

extern "C" void kernel_launch(void* const* d_in, const int* in_sizes, int n_in,
                              void* d_out, int out_size, void* d_ws, size_t ws_size,
                              hipStream_t stream) {
    const float* x      = (const float*)d_in[0];
    const float* rmsw   = (const float*)d_in[1];
    const float* ppre   = (const float*)d_in[2];
    const float* ppost  = (const float*)d_in[3];
    const float* pres   = (const float*)d_in[4];
    const float* b_pre  = (const float*)d_in[5];
    const float* b_post = (const float*)d_in[6];
    const float* b_res  = (const float*)d_in[7];
    const float* a_pre  = (const float*)d_in[8];
    const float* a_post = (const float*)d_in[9];
    const float* a_res  = (const float*)d_in[10];
    float* ws  = (float*)d_ws;
    float* out = (float*)d_out;

    const int nred = (NJ * ROWS_TOTAL + NTHREADS - 1) / NTHREADS;   // 400
    const size_t need16 = (size_t)(16 + 1) * NJ * ROWS_TOTAL * 4;   // 13.9 MB
    if (ws_size >= need16) {
        float* dsum = ws + (size_t)16 * NJ * ROWS_TOTAL;
        hipLaunchKernelGGL((mhc_main<16>), dim3(64 * 16), dim3(NTHREADS), 0, stream,
                           x, rmsw, ppre, ppost, pres, ws);
        hipLaunchKernelGGL((mhc_reduce<16>), dim3(nred), dim3(NTHREADS), 0, stream,
                           ws, dsum);
        hipLaunchKernelGGL(mhc_epi, dim3(128), dim3(64), 0, stream,
                           dsum, b_pre, b_post, b_res, a_pre, a_post, a_res, out);
    } else {
        float* dsum = ws + (size_t)4 * NJ * ROWS_TOTAL;
        hipLaunchKernelGGL((mhc_main<4>), dim3(64 * 4), dim3(NTHREADS), 0, stream,
                           x, rmsw, ppre, ppost, pres, ws);
        hipLaunchKernelGGL((mhc_reduce<4>), dim3(nred), dim3(NTHREADS), 0, stream,
                           ws, dsum);
        hipLaunchKernelGGL(mhc_epi, dim3(128), dim3(64), 0, stream,
                           dsum, b_pre, b_post, b_res, a_pre, a_post, a_res, out);
    }
}